// Round 7
// baseline (475.958 us; speedup 1.0000x reference)
//
#include <hip/hip_runtime.h>

// WindowAttention3D: B=1024, N1=256, N2=128, C=128, NH=4, hd=32, nW=64
// out = [x (1024*256*128 f32)] ++ [attn (1024*4*256*128 f32)]
// R7: katt blocks grouped by window; each block processes 4 b's sharing one
//     bm slice (128 KB) -> bm served from L2/L3 instead of HBM re-fetch.

typedef __attribute__((ext_vector_type(8))) short s16x8;
typedef __attribute__((ext_vector_type(4))) short s16x4;
typedef __attribute__((ext_vector_type(4))) float f32x4;

static __device__ __forceinline__ unsigned short f2bf(float f) {
  union { float f; unsigned u; } v; v.f = f;
  unsigned r = v.u + 0x7FFFu + ((v.u >> 16) & 1u);
  return (unsigned short)(r >> 16);
}

static __device__ __forceinline__ s16x8 cvt8(f32x4 a0, f32x4 a1) {
  s16x8 r;
  r[0] = (short)f2bf(a0[0]); r[1] = (short)f2bf(a0[1]);
  r[2] = (short)f2bf(a0[2]); r[3] = (short)f2bf(a0[3]);
  r[4] = (short)f2bf(a1[0]); r[5] = (short)f2bf(a1[1]);
  r[6] = (short)f2bf(a1[2]); r[7] = (short)f2bf(a1[3]);
  return r;
}

// ---------------- prep: weights->bf16, combined bias+mask table ----------------
__global__ void kw_prep(const float* __restrict__ qw, const float* __restrict__ kvw,
                        const float* __restrict__ pw, const float* __restrict__ rpb,
                        const int* __restrict__ relidx, const float* __restrict__ mask,
                        unsigned short* __restrict__ qwb, unsigned short* __restrict__ kvwb,
                        unsigned short* __restrict__ pwb, float* __restrict__ bm) {
  int tid = blockIdx.x * 256 + threadIdx.x;
  int stride = gridDim.x * 256;
  for (int i = tid; i < 65536; i += stride) {
    if (i < 16384)      qwb[i] = f2bf(qw[i]);
    else if (i < 49152) kvwb[i - 16384] = f2bf(kvw[i - 16384]);
    else                pwb[i - 49152] = f2bf(pw[i - 49152]);
  }
  for (int i = tid; i < 2097152; i += stride) {
    int wdw = i >> 15, j = i & 32767;
    int rel = relidx[j];
    float4 tv = *(const float4*)(rpb + rel * 4);
    float mk = mask[i];
    float* d = bm + (size_t)(wdw * 4) * 32768 + j;
    d[0]      = tv.x + mk;
    d[32768]  = tv.y + mk;
    d[65536]  = tv.z + mk;
    d[98304]  = tv.w + mk;
  }
}

// ---------------- q projection: qh[b][h][q][32] = (q @ qw^T + qb) * scale ----------------
__global__ __launch_bounds__(256) void kq(const float* __restrict__ q,
    const unsigned short* __restrict__ qwb, const float* __restrict__ qb,
    unsigned short* __restrict__ qh) {
  __shared__ unsigned short oL[64][136];
  int b = blockIdx.x >> 2, q0 = (blockIdx.x & 3) << 6;
  int t = threadIdx.x;
  int w = t >> 6, l = t & 63, lm = l & 15, lg = l >> 4;
  const float* arow = q + (size_t)(b * 256 + q0 + w * 16 + lm) * 128;
  f32x4 acc[8];
#pragma unroll
  for (int i = 0; i < 8; ++i) acc[i] = (f32x4){0.f, 0.f, 0.f, 0.f};
#pragma unroll
  for (int kk = 0; kk < 4; ++kk) {
    f32x4 a0 = __builtin_nontemporal_load((const f32x4*)(arow + kk * 32 + lg * 8));
    f32x4 a1 = __builtin_nontemporal_load((const f32x4*)(arow + kk * 32 + lg * 8 + 4));
    s16x8 a = cvt8(a0, a1);
#pragma unroll
    for (int ct = 0; ct < 8; ++ct) {
      s16x8 bf = *(const s16x8*)(qwb + (ct * 16 + lm) * 128 + kk * 32 + lg * 8);
      acc[ct] = __builtin_amdgcn_mfma_f32_16x16x32_bf16(a, bf, acc[ct], 0, 0, 0);
    }
  }
  const float SC = 0.17677669529663687f;   // 32^-0.5
#pragma unroll
  for (int ct = 0; ct < 8; ++ct) {
    int col = ct * 16 + lm;
    float bb = qb[col];
#pragma unroll
    for (int r = 0; r < 4; ++r)
      oL[w * 16 + lg * 4 + r][col] = f2bf((acc[ct][r] + bb) * SC);
  }
  __syncthreads();
  int o = t * 8, row = o >> 5, cs = o & 31;
#pragma unroll
  for (int h = 0; h < 4; ++h) {
    s16x8 v = *(const s16x8*)&oL[row][h * 32 + cs];
    *(s16x8*)(qh + ((size_t)(b * 4 + h) * 256 + q0 + row) * 32 + cs) = v;
  }
}

// ---------------- kv projection: kws[b][h][n2][32], vT[b][h][dh][n2] ----------------
__global__ __launch_bounds__(256) void kkv(const float* __restrict__ kv,
    const unsigned short* __restrict__ kvwb, const float* __restrict__ kvb,
    unsigned short* __restrict__ kws, unsigned short* __restrict__ vT) {
  __shared__ unsigned short oK[64][136];
  __shared__ unsigned short oV[128][72];
  int b = blockIdx.x >> 1, r0 = (blockIdx.x & 1) << 6;
  int t = threadIdx.x;
  int w = t >> 6, l = t & 63, lm = l & 15, lg = l >> 4;
  const float* arow = kv + (size_t)(b * 128 + r0 + w * 16 + lm) * 128;
  f32x4 acc[16];
#pragma unroll
  for (int i = 0; i < 16; ++i) acc[i] = (f32x4){0.f, 0.f, 0.f, 0.f};
#pragma unroll
  for (int kk = 0; kk < 4; ++kk) {
    f32x4 a0 = __builtin_nontemporal_load((const f32x4*)(arow + kk * 32 + lg * 8));
    f32x4 a1 = __builtin_nontemporal_load((const f32x4*)(arow + kk * 32 + lg * 8 + 4));
    s16x8 a = cvt8(a0, a1);
#pragma unroll
    for (int ct = 0; ct < 16; ++ct) {
      s16x8 bf = *(const s16x8*)(kvwb + (ct * 16 + lm) * 128 + kk * 32 + lg * 8);
      acc[ct] = __builtin_amdgcn_mfma_f32_16x16x32_bf16(a, bf, acc[ct], 0, 0, 0);
    }
  }
#pragma unroll
  for (int ct = 0; ct < 16; ++ct) {
    int col = ct * 16 + lm;
    float bb = kvb[col];
    if (col < 128) {
#pragma unroll
      for (int r = 0; r < 4; ++r)
        oK[w * 16 + lg * 4 + r][col] = f2bf(acc[ct][r] + bb);
    } else {
      int d = col - 128;
      s16x4 pk;
#pragma unroll
      for (int r = 0; r < 4; ++r) pk[r] = (short)f2bf(acc[ct][r] + bb);
      *(s16x4*)&oV[d][w * 16 + lg * 4] = pk;
    }
  }
  __syncthreads();
  {
    int o = t * 8, row = o >> 5, cs = o & 31;
#pragma unroll
    for (int h = 0; h < 4; ++h) {
      s16x8 v = *(const s16x8*)&oK[row][h * 32 + cs];
      *(s16x8*)(kws + ((size_t)(b * 4 + h) * 128 + r0 + row) * 32 + cs) = v;
    }
  }
#pragma unroll
  for (int i = 0; i < 4; ++i) {
    int o = (t + i * 256) * 8;
    int d = o >> 6, ns = o & 63;
    s16x8 v = *(const s16x8*)&oV[d][ns];
    *(s16x8*)(vT + ((size_t)b * 128 + d) * 128 + r0 + ns) = v;
  }
}

// ---------------- fused attention: block = (window, h, bg), loops 4 b's ----------------
__global__ __launch_bounds__(256) void katt6(const unsigned short* __restrict__ qh,
    const unsigned short* __restrict__ kws, const unsigned short* __restrict__ vT,
    const float* __restrict__ bm, float* __restrict__ attn_out,
    unsigned short* __restrict__ xp) {
  __shared__ float scratch[4][2176] __attribute__((aligned(16)));
  int blk = blockIdx.x;
  int widx = blk >> 4, h = (blk >> 2) & 3, bg = blk & 3;
  int t = threadIdx.x;
  int w = t >> 6, l = t & 63, lm = l & 15, lg = l >> 4;
  const float* bmh = bm + ((size_t)widx * 4 + h) * 32768;
  float* aSt = scratch[w];
  unsigned short* xSt = (unsigned short*)scratch[w];
  const f32x4 zero = {0.f, 0.f, 0.f, 0.f};

  for (int j = 0; j < 4; ++j) {
    int b = widx + 64 * (bg * 4 + j);
    const unsigned short* ksrc = kws + (size_t)(b * 4 + h) * 4096;
    const unsigned short* vsrc = vT + (size_t)(b * 4 + h) * 4096;
    const unsigned short* qsrc = qh + (size_t)(b * 4 + h) * 8192;
    float* attnh = attn_out + (size_t)(b * 4 + h) * 32768;

    for (int p = 0; p < 2; ++p) {
      int qbase = p * 128 + w * 32;
      s16x8 pfrag[2][4];
#pragma unroll
      for (int qt = 0; qt < 2; ++qt) {
        int q = qbase + qt * 16 + lm;
        s16x8 bq = __builtin_nontemporal_load((const s16x8*)(qsrc + q * 32 + lg * 8));
        f32x4 S[8];  // S^T: row n2 = ct*16+lg*4+r, col q = lm
#pragma unroll
        for (int ct = 0; ct < 8; ++ct) {
          s16x8 ak = *(const s16x8*)(ksrc + (ct * 16 + lm) * 32 + lg * 8);
          S[ct] = __builtin_amdgcn_mfma_f32_16x16x32_bf16(ak, bq, zero, 0, 0, 0);
        }
        float m = -1e30f;
#pragma unroll
        for (int ct = 0; ct < 8; ++ct) {
          float4 bv = *(const float4*)(bmh + q * 128 + ct * 16 + lg * 4);
          S[ct][0] += bv.x; S[ct][1] += bv.y; S[ct][2] += bv.z; S[ct][3] += bv.w;
          m = fmaxf(m, fmaxf(fmaxf(S[ct][0], S[ct][1]), fmaxf(S[ct][2], S[ct][3])));
        }
        m = fmaxf(m, __shfl_xor(m, 16));
        m = fmaxf(m, __shfl_xor(m, 32));
        float s = 0.f;
#pragma unroll
        for (int ct = 0; ct < 8; ++ct) {
#pragma unroll
          for (int r = 0; r < 4; ++r) { S[ct][r] = __expf(S[ct][r] - m); s += S[ct][r]; }
        }
        s += __shfl_xor(s, 16);
        s += __shfl_xor(s, 32);
        float inv = 1.0f / s;
#pragma unroll
        for (int ct = 0; ct < 8; ++ct) {
          f32x4 pv = { S[ct][0] * inv, S[ct][1] * inv, S[ct][2] * inv, S[ct][3] * inv };
          *(f32x4*)(aSt + lm * 136 + ct * 16 + lg * 4) = pv;
        }
        float* adst = attnh + (qbase + qt * 16) * 128;
#pragma unroll
        for (int i = 0; i < 8; ++i) {
          int o = l * 4 + i * 256;
          int row = o >> 7, colf = o & 127;
          f32x4 v = *(const f32x4*)(aSt + row * 136 + colf);
          __builtin_nontemporal_store(v, (f32x4*)(adst + o));
        }
#pragma unroll
        for (int kk = 0; kk < 4; ++kk) {
          const float* pp = aSt + lm * 136 + kk * 32 + lg * 8;
          pfrag[qt][kk] = cvt8(*(const f32x4*)pp, *(const f32x4*)(pp + 4));
        }
      }
      // ---- O^T = vT @ P^T ----
      f32x4 O[2][2];
#pragma unroll
      for (int cd = 0; cd < 2; ++cd)
#pragma unroll
        for (int qt = 0; qt < 2; ++qt) O[cd][qt] = zero;
#pragma unroll
      for (int kk = 0; kk < 4; ++kk) {
        s16x8 av[2];
#pragma unroll
        for (int cd = 0; cd < 2; ++cd)
          av[cd] = *(const s16x8*)(vsrc + (cd * 16 + lm) * 128 + kk * 32 + lg * 8);
#pragma unroll
        for (int cd = 0; cd < 2; ++cd)
#pragma unroll
          for (int qt = 0; qt < 2; ++qt)
            O[cd][qt] = __builtin_amdgcn_mfma_f32_16x16x32_bf16(av[cd], pfrag[qt][kk], O[cd][qt], 0, 0, 0);
      }
#pragma unroll
      for (int qt = 0; qt < 2; ++qt)
#pragma unroll
        for (int cd = 0; cd < 2; ++cd) {
          s16x4 pk;
#pragma unroll
          for (int r = 0; r < 4; ++r) pk[r] = (short)f2bf(O[cd][qt][r]);
          *(s16x4*)(xSt + (qt * 16 + lm) * 40 + cd * 16 + lg * 4) = pk;
        }
      unsigned short* xdst = xp + ((size_t)(b * 4 + h) * 256 + qbase) * 32;
#pragma unroll
      for (int i = 0; i < 2; ++i) {
        int o = l * 8 + i * 512;
        int row = o >> 5, cs = o & 31;
        s16x8 v = *(const s16x8*)(xSt + row * 40 + cs);
        *(s16x8*)(xdst + o) = v;
      }
    }
  }
}

// ---------------- output projection: x = xp @ pw^T + pb (f32 out) ----------------
__global__ __launch_bounds__(256) void kp(const unsigned short* __restrict__ xp,
    const unsigned short* __restrict__ pwb, const float* __restrict__ pb,
    float* __restrict__ xout) {
  __shared__ float oX[64][132];
  int b = blockIdx.x >> 2, r0 = (blockIdx.x & 3) << 6;
  int t = threadIdx.x;
  int w = t >> 6, l = t & 63, lm = l & 15, lg = l >> 4;
  f32x4 acc[8];
#pragma unroll
  for (int i = 0; i < 8; ++i) acc[i] = (f32x4){0.f, 0.f, 0.f, 0.f};
#pragma unroll
  for (int kk = 0; kk < 4; ++kk) {
    s16x8 a = *(const s16x8*)(xp + ((size_t)(b * 4 + kk) * 256 + r0 + w * 16 + lm) * 32 + lg * 8);
#pragma unroll
    for (int ct = 0; ct < 8; ++ct) {
      s16x8 bf = *(const s16x8*)(pwb + (ct * 16 + lm) * 128 + kk * 32 + lg * 8);
      acc[ct] = __builtin_amdgcn_mfma_f32_16x16x32_bf16(a, bf, acc[ct], 0, 0, 0);
    }
  }
#pragma unroll
  for (int ct = 0; ct < 8; ++ct) {
    int col = ct * 16 + lm;
    float bb = pb[col];
#pragma unroll
    for (int r = 0; r < 4; ++r)
      oX[w * 16 + lg * 4 + r][col] = acc[ct][r] + bb;
  }
  __syncthreads();
  float* xdst = xout + ((size_t)b * 256 + r0) * 128;
#pragma unroll
  for (int i = 0; i < 8; ++i) {
    int o = (t + i * 256) * 4;
    int row = o >> 7, colf = o & 127;
    f32x4 v = *(const f32x4*)&oX[row][colf];
    __builtin_nontemporal_store(v, (f32x4*)(xdst + o));
  }
}

extern "C" void kernel_launch(void* const* d_in, const int* in_sizes, int n_in,
                              void* d_out, int out_size, void* d_ws, size_t ws_size,
                              hipStream_t stream) {
  const float* q    = (const float*)d_in[0];
  const float* kv   = (const float*)d_in[1];
  const float* mask = (const float*)d_in[2];
  const float* qw   = (const float*)d_in[3];
  const float* qb   = (const float*)d_in[4];
  const float* kvw  = (const float*)d_in[5];
  const float* kvb  = (const float*)d_in[6];
  const float* pw   = (const float*)d_in[7];
  const float* pb   = (const float*)d_in[8];
  const float* rpb  = (const float*)d_in[9];
  const int* relidx = (const int*)d_in[10];

  float* xout = (float*)d_out;
  float* attn = xout + (size_t)1024 * 256 * 128;   // 33,554,432

  char* ws = (char*)d_ws;
  unsigned short* qwb  = (unsigned short*)ws;                 // 32 KB
  unsigned short* kvwb = (unsigned short*)(ws + 32768);       // 64 KB
  unsigned short* pwb  = (unsigned short*)(ws + 98304);       // 32 KB
  float*          bm   = (float*)(ws + 131072);               // 32 MB
  unsigned short* qh   = (unsigned short*)(ws + 131072 + 33554432);  // 64 MB
  unsigned short* kws  = qh  + (size_t)33554432;              // 32 MB
  unsigned short* vT   = kws + (size_t)16777216;              // 32 MB
  unsigned short* xp   = vT  + (size_t)16777216;              // 64 MB

  kw_prep<<<2048, 256, 0, stream>>>(qw, kvw, pw, rpb, relidx, mask, qwb, kvwb, pwb, bm);
  kq<<<4096, 256, 0, stream>>>(q, qwb, qb, qh);
  kkv<<<2048, 256, 0, stream>>>(kv, kvwb, kvb, kws, vT);
  katt6<<<1024, 256, 0, stream>>>(qh, kws, vT, bm, attn, xp);
  kp<<<4096, 256, 0, stream>>>(xp, pwb, pb, xout);
}

// Round 8
// 420.283 us; speedup vs baseline: 1.1325x; 1.1325x over previous
//
#include <hip/hip_runtime.h>

// WindowAttention3D: B=1024, N1=256, N2=128, C=128, NH=4, hd=32, nW=64
// out = [x (1024*256*128 f32)] ++ [attn (1024*4*256*128 f32)]
// R8: single fused kernel (q-proj + attention + out-proj) per (b, 64 q rows);
//     qh/xp HBM round-trips eliminated; kkv + prep unchanged.

typedef __attribute__((ext_vector_type(8))) short s16x8;
typedef __attribute__((ext_vector_type(4))) short s16x4;
typedef __attribute__((ext_vector_type(4))) float f32x4;

static __device__ __forceinline__ unsigned short f2bf(float f) {
  union { float f; unsigned u; } v; v.f = f;
  unsigned r = v.u + 0x7FFFu + ((v.u >> 16) & 1u);
  return (unsigned short)(r >> 16);
}

static __device__ __forceinline__ s16x8 cvt8(f32x4 a0, f32x4 a1) {
  s16x8 r;
  r[0] = (short)f2bf(a0[0]); r[1] = (short)f2bf(a0[1]);
  r[2] = (short)f2bf(a0[2]); r[3] = (short)f2bf(a0[3]);
  r[4] = (short)f2bf(a1[0]); r[5] = (short)f2bf(a1[1]);
  r[6] = (short)f2bf(a1[2]); r[7] = (short)f2bf(a1[3]);
  return r;
}

// ---------------- prep: weights->bf16, combined bias+mask table ----------------
// bm[w][h][q][n2] = rpb[rel_index[q][n2]][h] + mask[w][q][n2]   (f32, 32 MB)
__global__ void kw_prep(const float* __restrict__ qw, const float* __restrict__ kvw,
                        const float* __restrict__ pw, const float* __restrict__ rpb,
                        const int* __restrict__ relidx, const float* __restrict__ mask,
                        unsigned short* __restrict__ qwb, unsigned short* __restrict__ kvwb,
                        unsigned short* __restrict__ pwb, float* __restrict__ bm) {
  int tid = blockIdx.x * 256 + threadIdx.x;
  int stride = gridDim.x * 256;
  for (int i = tid; i < 65536; i += stride) {
    if (i < 16384)      qwb[i] = f2bf(qw[i]);
    else if (i < 49152) kvwb[i - 16384] = f2bf(kvw[i - 16384]);
    else                pwb[i - 49152] = f2bf(pw[i - 49152]);
  }
  for (int i = tid; i < 2097152; i += stride) {
    int wdw = i >> 15, j = i & 32767;
    int rel = relidx[j];
    float4 tv = *(const float4*)(rpb + rel * 4);
    float mk = mask[i];
    float* d = bm + (size_t)(wdw * 4) * 32768 + j;
    d[0]      = tv.x + mk;
    d[32768]  = tv.y + mk;
    d[65536]  = tv.z + mk;
    d[98304]  = tv.w + mk;
  }
}

// ---------------- kv projection: kws[b][h][n2][32], vT[b][h][dh][n2] ----------------
__global__ __launch_bounds__(256) void kkv(const float* __restrict__ kv,
    const unsigned short* __restrict__ kvwb, const float* __restrict__ kvb,
    unsigned short* __restrict__ kws, unsigned short* __restrict__ vT) {
  __shared__ unsigned short oK[64][136];
  __shared__ unsigned short oV[128][72];
  int b = blockIdx.x >> 1, r0 = (blockIdx.x & 1) << 6;
  int t = threadIdx.x;
  int w = t >> 6, l = t & 63, lm = l & 15, lg = l >> 4;
  const float* arow = kv + (size_t)(b * 128 + r0 + w * 16 + lm) * 128;
  f32x4 acc[16];
#pragma unroll
  for (int i = 0; i < 16; ++i) acc[i] = (f32x4){0.f, 0.f, 0.f, 0.f};
#pragma unroll
  for (int kk = 0; kk < 4; ++kk) {
    f32x4 a0 = __builtin_nontemporal_load((const f32x4*)(arow + kk * 32 + lg * 8));
    f32x4 a1 = __builtin_nontemporal_load((const f32x4*)(arow + kk * 32 + lg * 8 + 4));
    s16x8 a = cvt8(a0, a1);
#pragma unroll
    for (int ct = 0; ct < 16; ++ct) {
      s16x8 bf = *(const s16x8*)(kvwb + (ct * 16 + lm) * 128 + kk * 32 + lg * 8);
      acc[ct] = __builtin_amdgcn_mfma_f32_16x16x32_bf16(a, bf, acc[ct], 0, 0, 0);
    }
  }
#pragma unroll
  for (int ct = 0; ct < 16; ++ct) {
    int col = ct * 16 + lm;
    float bb = kvb[col];
    if (col < 128) {
#pragma unroll
      for (int r = 0; r < 4; ++r)
        oK[w * 16 + lg * 4 + r][col] = f2bf(acc[ct][r] + bb);
    } else {
      int d = col - 128;
      s16x4 pk;
#pragma unroll
      for (int r = 0; r < 4; ++r) pk[r] = (short)f2bf(acc[ct][r] + bb);
      *(s16x4*)&oV[d][w * 16 + lg * 4] = pk;
    }
  }
  __syncthreads();
  {
    int o = t * 8, row = o >> 5, cs = o & 31;
#pragma unroll
    for (int h = 0; h < 4; ++h) {
      s16x8 v = *(const s16x8*)&oK[row][h * 32 + cs];
      *(s16x8*)(kws + ((size_t)(b * 4 + h) * 128 + r0 + row) * 32 + cs) = v;
    }
  }
#pragma unroll
  for (int i = 0; i < 4; ++i) {
    int o = (t + i * 256) * 8;
    int d = o >> 6, ns = o & 63;
    s16x8 v = *(const s16x8*)&oV[d][ns];
    *(s16x8*)(vT + ((size_t)b * 128 + d) * 128 + r0 + ns) = v;
  }
}

// ---------------- fused: q-proj + attention + out-proj per (b, 64 q rows) ----------------
__global__ __launch_bounds__(256) void kfused(const float* __restrict__ q,
    const unsigned short* __restrict__ qwb, const float* __restrict__ qb,
    const unsigned short* __restrict__ kws, const unsigned short* __restrict__ vT,
    const float* __restrict__ bm, const unsigned short* __restrict__ pwb,
    const float* __restrict__ pb, float* __restrict__ attn_out,
    float* __restrict__ xout) {
  __shared__ unsigned short qhL[64][136];   // qh tile, all heads
  __shared__ unsigned short XL[64][136];    // attention output tile, all heads
  __shared__ float scratch[4][2176] __attribute__((aligned(16))); // per-wave aSt[16][136] / block oX[64][132]
  int bid = blockIdx.x;
  // XCD-aware mapping: 4 q-blocks of one b land on one XCD, dispatched adjacently
  int xcd = bid & 7, g = bid >> 3;
  int b = xcd * 128 + (g >> 2), qq = g & 3;
  int q0 = qq * 64;
  int t = threadIdx.x;
  int w = t >> 6, l = t & 63, lm = l & 15, lg = l >> 4;
  const f32x4 zero = {0.f, 0.f, 0.f, 0.f};

  // ---- Phase 1: q-proj, wave w -> rows w*16..w*16+15 ----
  {
    const float* arow = q + (size_t)(b * 256 + q0 + w * 16 + lm) * 128;
    f32x4 acc[8];
#pragma unroll
    for (int i = 0; i < 8; ++i) acc[i] = zero;
#pragma unroll
    for (int kk = 0; kk < 4; ++kk) {
      f32x4 a0 = __builtin_nontemporal_load((const f32x4*)(arow + kk * 32 + lg * 8));
      f32x4 a1 = __builtin_nontemporal_load((const f32x4*)(arow + kk * 32 + lg * 8 + 4));
      s16x8 a = cvt8(a0, a1);
#pragma unroll
      for (int ct = 0; ct < 8; ++ct) {
        s16x8 bf = *(const s16x8*)(qwb + (ct * 16 + lm) * 128 + kk * 32 + lg * 8);
        acc[ct] = __builtin_amdgcn_mfma_f32_16x16x32_bf16(a, bf, acc[ct], 0, 0, 0);
      }
    }
    const float SC = 0.17677669529663687f;   // 32^-0.5
#pragma unroll
    for (int ct = 0; ct < 8; ++ct) {
      int col = ct * 16 + lm;
      float bb = qb[col];
#pragma unroll
      for (int r = 0; r < 4; ++r)
        qhL[w * 16 + lg * 4 + r][col] = f2bf((acc[ct][r] + bb) * SC);
    }
  }
  __syncthreads();

  // ---- Phase 2: attention, wave w = head h, 4 subtiles of 16 q-rows ----
  {
    int h = w;
    const unsigned short* ksrc = kws + (size_t)(b * 4 + h) * 4096;
    const unsigned short* vsrc = vT + (size_t)(b * 4 + h) * 4096;
    const float* bmh = bm + (size_t)((b & 63) * 4 + h) * 32768;
    float* attnh = attn_out + ((size_t)(b * 4 + h) * 256 + q0) * 128;
    float* aSt = scratch[w];
    for (int qt = 0; qt < 4; ++qt) {
      int qg = q0 + qt * 16 + lm;            // global q row for B-operand lane
      s16x8 bq = *(const s16x8*)&qhL[qt * 16 + lm][h * 32 + lg * 8];
      f32x4 S[8];  // S^T: row n2 = ct*16+lg*4+r, col q = lm
#pragma unroll
      for (int ct = 0; ct < 8; ++ct) {
        s16x8 ak = *(const s16x8*)(ksrc + (ct * 16 + lm) * 32 + lg * 8);
        S[ct] = __builtin_amdgcn_mfma_f32_16x16x32_bf16(ak, bq, zero, 0, 0, 0);
      }
      float m = -1e30f;
#pragma unroll
      for (int ct = 0; ct < 8; ++ct) {
        float4 bv = *(const float4*)(bmh + (size_t)qg * 128 + ct * 16 + lg * 4);
        S[ct][0] += bv.x; S[ct][1] += bv.y; S[ct][2] += bv.z; S[ct][3] += bv.w;
        m = fmaxf(m, fmaxf(fmaxf(S[ct][0], S[ct][1]), fmaxf(S[ct][2], S[ct][3])));
      }
      m = fmaxf(m, __shfl_xor(m, 16));
      m = fmaxf(m, __shfl_xor(m, 32));
      float s = 0.f;
#pragma unroll
      for (int ct = 0; ct < 8; ++ct) {
#pragma unroll
        for (int r = 0; r < 4; ++r) { S[ct][r] = __expf(S[ct][r] - m); s += S[ct][r]; }
      }
      s += __shfl_xor(s, 16);
      s += __shfl_xor(s, 32);
      float inv = 1.0f / s;
      // stage P f32 into per-wave aSt (row = q local = lm, cols n2)
#pragma unroll
      for (int ct = 0; ct < 8; ++ct) {
        f32x4 pv = { S[ct][0] * inv, S[ct][1] * inv, S[ct][2] * inv, S[ct][3] * inv };
        *(f32x4*)(aSt + lm * 136 + ct * 16 + lg * 4) = pv;
      }
      // coalesced NT attn store: 16 rows x 512B contiguous
      float* adst = attnh + qt * 16 * 128;
#pragma unroll
      for (int i = 0; i < 8; ++i) {
        int o = l * 4 + i * 256;
        int row = o >> 7, colf = o & 127;
        f32x4 v = *(const f32x4*)(aSt + row * 136 + colf);
        __builtin_nontemporal_store(v, (f32x4*)(adst + o));
      }
      // P fragments + PV
      f32x4 O[2];
      O[0] = zero; O[1] = zero;
#pragma unroll
      for (int kk = 0; kk < 4; ++kk) {
        const float* pp = aSt + lm * 136 + kk * 32 + lg * 8;
        s16x8 pf = cvt8(*(const f32x4*)pp, *(const f32x4*)(pp + 4));
#pragma unroll
        for (int cd = 0; cd < 2; ++cd) {
          s16x8 av = *(const s16x8*)(vsrc + (cd * 16 + lm) * 128 + kk * 32 + lg * 8);
          O[cd] = __builtin_amdgcn_mfma_f32_16x16x32_bf16(av, pf, O[cd], 0, 0, 0);
        }
      }
      // X tile: row q local, col = h*32 + d
#pragma unroll
      for (int cd = 0; cd < 2; ++cd) {
        s16x4 pk;
#pragma unroll
        for (int r = 0; r < 4; ++r) pk[r] = (short)f2bf(O[cd][r]);
        *(s16x4*)&XL[qt * 16 + lm][h * 32 + cd * 16 + lg * 4] = pk;
      }
    }
  }
  __syncthreads();

  // ---- Phase 3: out-proj, wave w -> rows w*16..w*16+15 ----
  float (*oX)[132] = (float(*)[132])scratch;
  {
    f32x4 acc[8];
#pragma unroll
    for (int i = 0; i < 8; ++i) acc[i] = zero;
#pragma unroll
    for (int kk = 0; kk < 4; ++kk) {
      s16x8 a = *(const s16x8*)&XL[w * 16 + lm][kk * 32 + lg * 8];
#pragma unroll
      for (int ct = 0; ct < 8; ++ct) {
        s16x8 bf = *(const s16x8*)(pwb + (ct * 16 + lm) * 128 + kk * 32 + lg * 8);
        acc[ct] = __builtin_amdgcn_mfma_f32_16x16x32_bf16(a, bf, acc[ct], 0, 0, 0);
      }
    }
#pragma unroll
    for (int ct = 0; ct < 8; ++ct) {
      int col = ct * 16 + lm;
      float bb = pb[col];
#pragma unroll
      for (int r = 0; r < 4; ++r)
        oX[w * 16 + lg * 4 + r][col] = acc[ct][r] + bb;
    }
  }
  __syncthreads();
  float* xdst = xout + ((size_t)b * 256 + q0) * 128;
#pragma unroll
  for (int i = 0; i < 8; ++i) {
    int o = (t + i * 256) * 4;
    int row = o >> 7, colf = o & 127;
    f32x4 v = *(const f32x4*)&oX[row][colf];
    __builtin_nontemporal_store(v, (f32x4*)(xdst + o));
  }
}

extern "C" void kernel_launch(void* const* d_in, const int* in_sizes, int n_in,
                              void* d_out, int out_size, void* d_ws, size_t ws_size,
                              hipStream_t stream) {
  const float* q    = (const float*)d_in[0];
  const float* kv   = (const float*)d_in[1];
  const float* mask = (const float*)d_in[2];
  const float* qw   = (const float*)d_in[3];
  const float* qb   = (const float*)d_in[4];
  const float* kvw  = (const float*)d_in[5];
  const float* kvb  = (const float*)d_in[6];
  const float* pw   = (const float*)d_in[7];
  const float* pb   = (const float*)d_in[8];
  const float* rpb  = (const float*)d_in[9];
  const int* relidx = (const int*)d_in[10];

  float* xout = (float*)d_out;
  float* attn = xout + (size_t)1024 * 256 * 128;   // 33,554,432

  char* ws = (char*)d_ws;
  unsigned short* qwb  = (unsigned short*)ws;                 // 32 KB
  unsigned short* kvwb = (unsigned short*)(ws + 32768);       // 64 KB
  unsigned short* pwb  = (unsigned short*)(ws + 98304);       // 32 KB
  float*          bm   = (float*)(ws + 131072);               // 32 MB
  unsigned short* kws  = (unsigned short*)(ws + 131072 + 33554432);  // 32 MB
  unsigned short* vT   = kws + (size_t)16777216;              // 32 MB

  kw_prep<<<2048, 256, 0, stream>>>(qw, kvw, pw, rpb, relidx, mask, qwb, kvwb, pwb, bm);
  kkv<<<2048, 256, 0, stream>>>(kv, kvwb, kvb, kws, vT);
  kfused<<<4096, 256, 0, stream>>>(q, qwb, qb, kws, vT, bm, pwb, pb, attn, xout);
}

// Round 9
// 417.964 us; speedup vs baseline: 1.1388x; 1.0055x over previous
//
#include <hip/hip_runtime.h>

// WindowAttention3D: B=1024, N1=256, N2=128, C=128, NH=4, hd=32, nW=64
// out = [x (1024*256*128 f32)] ++ [attn (1024*4*256*128 f32)]
// R9: fused kernel with (a) plain (non-NT) full-line output stores,
//     (b) half-tile per-wave scratch -> LDS 52.2 KB -> 3 blocks/CU.

typedef __attribute__((ext_vector_type(8))) short s16x8;
typedef __attribute__((ext_vector_type(4))) short s16x4;
typedef __attribute__((ext_vector_type(4))) float f32x4;

static __device__ __forceinline__ unsigned short f2bf(float f) {
  union { float f; unsigned u; } v; v.f = f;
  unsigned r = v.u + 0x7FFFu + ((v.u >> 16) & 1u);
  return (unsigned short)(r >> 16);
}

static __device__ __forceinline__ s16x8 cvt8(f32x4 a0, f32x4 a1) {
  s16x8 r;
  r[0] = (short)f2bf(a0[0]); r[1] = (short)f2bf(a0[1]);
  r[2] = (short)f2bf(a0[2]); r[3] = (short)f2bf(a0[3]);
  r[4] = (short)f2bf(a1[0]); r[5] = (short)f2bf(a1[1]);
  r[6] = (short)f2bf(a1[2]); r[7] = (short)f2bf(a1[3]);
  return r;
}

// ---------------- prep: weights->bf16, combined bias+mask table ----------------
__global__ void kw_prep(const float* __restrict__ qw, const float* __restrict__ kvw,
                        const float* __restrict__ pw, const float* __restrict__ rpb,
                        const int* __restrict__ relidx, const float* __restrict__ mask,
                        unsigned short* __restrict__ qwb, unsigned short* __restrict__ kvwb,
                        unsigned short* __restrict__ pwb, float* __restrict__ bm) {
  int tid = blockIdx.x * 256 + threadIdx.x;
  int stride = gridDim.x * 256;
  for (int i = tid; i < 65536; i += stride) {
    if (i < 16384)      qwb[i] = f2bf(qw[i]);
    else if (i < 49152) kvwb[i - 16384] = f2bf(kvw[i - 16384]);
    else                pwb[i - 49152] = f2bf(pw[i - 49152]);
  }
  for (int i = tid; i < 2097152; i += stride) {
    int wdw = i >> 15, j = i & 32767;
    int rel = relidx[j];
    float4 tv = *(const float4*)(rpb + rel * 4);
    float mk = mask[i];
    float* d = bm + (size_t)(wdw * 4) * 32768 + j;
    d[0]      = tv.x + mk;
    d[32768]  = tv.y + mk;
    d[65536]  = tv.z + mk;
    d[98304]  = tv.w + mk;
  }
}

// ---------------- kv projection: kws[b][h][n2][32], vT[b][h][dh][n2] ----------------
__global__ __launch_bounds__(256) void kkv(const float* __restrict__ kv,
    const unsigned short* __restrict__ kvwb, const float* __restrict__ kvb,
    unsigned short* __restrict__ kws, unsigned short* __restrict__ vT) {
  __shared__ unsigned short oK[64][136];
  __shared__ unsigned short oV[128][72];
  int b = blockIdx.x >> 1, r0 = (blockIdx.x & 1) << 6;
  int t = threadIdx.x;
  int w = t >> 6, l = t & 63, lm = l & 15, lg = l >> 4;
  const float* arow = kv + (size_t)(b * 128 + r0 + w * 16 + lm) * 128;
  f32x4 acc[16];
#pragma unroll
  for (int i = 0; i < 16; ++i) acc[i] = (f32x4){0.f, 0.f, 0.f, 0.f};
#pragma unroll
  for (int kk = 0; kk < 4; ++kk) {
    f32x4 a0 = __builtin_nontemporal_load((const f32x4*)(arow + kk * 32 + lg * 8));
    f32x4 a1 = __builtin_nontemporal_load((const f32x4*)(arow + kk * 32 + lg * 8 + 4));
    s16x8 a = cvt8(a0, a1);
#pragma unroll
    for (int ct = 0; ct < 16; ++ct) {
      s16x8 bf = *(const s16x8*)(kvwb + (ct * 16 + lm) * 128 + kk * 32 + lg * 8);
      acc[ct] = __builtin_amdgcn_mfma_f32_16x16x32_bf16(a, bf, acc[ct], 0, 0, 0);
    }
  }
#pragma unroll
  for (int ct = 0; ct < 16; ++ct) {
    int col = ct * 16 + lm;
    float bb = kvb[col];
    if (col < 128) {
#pragma unroll
      for (int r = 0; r < 4; ++r)
        oK[w * 16 + lg * 4 + r][col] = f2bf(acc[ct][r] + bb);
    } else {
      int d = col - 128;
      s16x4 pk;
#pragma unroll
      for (int r = 0; r < 4; ++r) pk[r] = (short)f2bf(acc[ct][r] + bb);
      *(s16x4*)&oV[d][w * 16 + lg * 4] = pk;
    }
  }
  __syncthreads();
  {
    int o = t * 8, row = o >> 5, cs = o & 31;
#pragma unroll
    for (int h = 0; h < 4; ++h) {
      s16x8 v = *(const s16x8*)&oK[row][h * 32 + cs];
      *(s16x8*)(kws + ((size_t)(b * 4 + h) * 128 + r0 + row) * 32 + cs) = v;
    }
  }
#pragma unroll
  for (int i = 0; i < 4; ++i) {
    int o = (t + i * 256) * 8;
    int d = o >> 6, ns = o & 63;
    s16x8 v = *(const s16x8*)&oV[d][ns];
    *(s16x8*)(vT + ((size_t)b * 128 + d) * 128 + r0 + ns) = v;
  }
}

// ---------------- fused: q-proj + attention + out-proj per (b, 64 q rows) ----------------
__global__ __launch_bounds__(256, 3) void kfused(const float* __restrict__ q,
    const unsigned short* __restrict__ qwb, const float* __restrict__ qb,
    const unsigned short* __restrict__ kws, const unsigned short* __restrict__ vT,
    const float* __restrict__ bm, const unsigned short* __restrict__ pwb,
    const float* __restrict__ pb, float* __restrict__ attn_out,
    float* __restrict__ xout) {
  __shared__ unsigned short qhL[64][136];   // qh tile, all heads
  __shared__ unsigned short XL[64][136];    // attention output tile, all heads
  __shared__ float scratch[4][1088] __attribute__((aligned(16))); // per-wave aSt[16][68]
  int bid = blockIdx.x;
  int xcd = bid & 7, g = bid >> 3;
  int b = xcd * 128 + (g >> 2), qq = g & 3;
  int q0 = qq * 64;
  int t = threadIdx.x;
  int w = t >> 6, l = t & 63, lm = l & 15, lg = l >> 4;
  float* aSt = scratch[w];                  // [16][68] f32
  const f32x4 zero = {0.f, 0.f, 0.f, 0.f};

  // ---- Phase 1: q-proj, wave w -> rows w*16..w*16+15 ----
  {
    const float* arow = q + (size_t)(b * 256 + q0 + w * 16 + lm) * 128;
    f32x4 acc[8];
#pragma unroll
    for (int i = 0; i < 8; ++i) acc[i] = zero;
#pragma unroll
    for (int kk = 0; kk < 4; ++kk) {
      f32x4 a0 = __builtin_nontemporal_load((const f32x4*)(arow + kk * 32 + lg * 8));
      f32x4 a1 = __builtin_nontemporal_load((const f32x4*)(arow + kk * 32 + lg * 8 + 4));
      s16x8 a = cvt8(a0, a1);
#pragma unroll
      for (int ct = 0; ct < 8; ++ct) {
        s16x8 bf = *(const s16x8*)(qwb + (ct * 16 + lm) * 128 + kk * 32 + lg * 8);
        acc[ct] = __builtin_amdgcn_mfma_f32_16x16x32_bf16(a, bf, acc[ct], 0, 0, 0);
      }
    }
    const float SC = 0.17677669529663687f;   // 32^-0.5
#pragma unroll
    for (int ct = 0; ct < 8; ++ct) {
      int col = ct * 16 + lm;
      float bb = qb[col];
#pragma unroll
      for (int r = 0; r < 4; ++r)
        qhL[w * 16 + lg * 4 + r][col] = f2bf((acc[ct][r] + bb) * SC);
    }
  }
  __syncthreads();

  // ---- Phase 2: attention, wave w = head h, 4 subtiles of 16 q-rows ----
  {
    int h = w;
    const unsigned short* ksrc = kws + (size_t)(b * 4 + h) * 4096;
    const unsigned short* vsrc = vT + (size_t)(b * 4 + h) * 4096;
    const float* bmh = bm + (size_t)((b & 63) * 4 + h) * 32768;
    float* attnh = attn_out + ((size_t)(b * 4 + h) * 256 + q0) * 128;
    for (int qt = 0; qt < 4; ++qt) {
      int qg = q0 + qt * 16 + lm;
      s16x8 bq = *(const s16x8*)&qhL[qt * 16 + lm][h * 32 + lg * 8];
      f32x4 S[8];  // S^T: row n2 = ct*16+lg*4+r, col q = lm
#pragma unroll
      for (int ct = 0; ct < 8; ++ct) {
        s16x8 ak = *(const s16x8*)(ksrc + (ct * 16 + lm) * 32 + lg * 8);
        S[ct] = __builtin_amdgcn_mfma_f32_16x16x32_bf16(ak, bq, zero, 0, 0, 0);
      }
      float m = -1e30f;
#pragma unroll
      for (int ct = 0; ct < 8; ++ct) {
        float4 bv = *(const float4*)(bmh + (size_t)qg * 128 + ct * 16 + lg * 4);
        S[ct][0] += bv.x; S[ct][1] += bv.y; S[ct][2] += bv.z; S[ct][3] += bv.w;
        m = fmaxf(m, fmaxf(fmaxf(S[ct][0], S[ct][1]), fmaxf(S[ct][2], S[ct][3])));
      }
      m = fmaxf(m, __shfl_xor(m, 16));
      m = fmaxf(m, __shfl_xor(m, 32));
      float s = 0.f;
#pragma unroll
      for (int ct = 0; ct < 8; ++ct) {
#pragma unroll
        for (int r = 0; r < 4; ++r) { S[ct][r] = __expf(S[ct][r] - m); s += S[ct][r]; }
      }
      s += __shfl_xor(s, 16);
      s += __shfl_xor(s, 32);
      float inv = 1.0f / s;
      float* adst = attnh + qt * 16 * 128;
      s16x8 pfrag[4];
      // two half-tiles of 16 q-rows x 64 n2 through per-wave aSt
#pragma unroll
      for (int half = 0; half < 2; ++half) {
#pragma unroll
        for (int c = 0; c < 4; ++c) {
          int ct = half * 4 + c;
          f32x4 pv = { S[ct][0] * inv, S[ct][1] * inv, S[ct][2] * inv, S[ct][3] * inv };
          *(f32x4*)(aSt + lm * 68 + c * 16 + lg * 4) = pv;
        }
        // store: 16 rows x 256B (each segment = 2 full 128B lines)
#pragma unroll
        for (int i = 0; i < 4; ++i) {
          int o = l * 4 + i * 256;
          int row = o >> 6, col = o & 63;
          f32x4 v = *(const f32x4*)(aSt + row * 68 + col);
          *(f32x4*)(adst + row * 128 + half * 64 + col) = v;
        }
        // P fragments for this half (k-slices half*2, half*2+1)
#pragma unroll
        for (int k2 = 0; k2 < 2; ++k2) {
          const float* pp = aSt + lm * 68 + k2 * 32 + lg * 8;
          pfrag[half * 2 + k2] = cvt8(*(const f32x4*)pp, *(const f32x4*)(pp + 4));
        }
      }
      // PV
      f32x4 O[2];
      O[0] = zero; O[1] = zero;
#pragma unroll
      for (int kk = 0; kk < 4; ++kk) {
#pragma unroll
        for (int cd = 0; cd < 2; ++cd) {
          s16x8 av = *(const s16x8*)(vsrc + (cd * 16 + lm) * 128 + kk * 32 + lg * 8);
          O[cd] = __builtin_amdgcn_mfma_f32_16x16x32_bf16(av, pfrag[kk], O[cd], 0, 0, 0);
        }
      }
#pragma unroll
      for (int cd = 0; cd < 2; ++cd) {
        s16x4 pk;
#pragma unroll
        for (int r = 0; r < 4; ++r) pk[r] = (short)f2bf(O[cd][r]);
        *(s16x4*)&XL[qt * 16 + lm][h * 32 + cd * 16 + lg * 4] = pk;
      }
    }
  }
  __syncthreads();

  // ---- Phase 3: out-proj, wave w -> rows w*16..w*16+15 ----
  {
    f32x4 acc[8];
#pragma unroll
    for (int i = 0; i < 8; ++i) acc[i] = zero;
#pragma unroll
    for (int kk = 0; kk < 4; ++kk) {
      s16x8 a = *(const s16x8*)&XL[w * 16 + lm][kk * 32 + lg * 8];
#pragma unroll
      for (int ct = 0; ct < 8; ++ct) {
        s16x8 bf = *(const s16x8*)(pwb + (ct * 16 + lm) * 128 + kk * 32 + lg * 8);
        acc[ct] = __builtin_amdgcn_mfma_f32_16x16x32_bf16(a, bf, acc[ct], 0, 0, 0);
      }
    }
#pragma unroll
    for (int ct = 0; ct < 8; ++ct) {
      int col = ct * 16 + lm;
      float bb = pb[col];
#pragma unroll
      for (int r = 0; r < 4; ++r) acc[ct][r] += bb;
    }
    float* xdst = xout + ((size_t)b * 256 + q0 + w * 16) * 128;
#pragma unroll
    for (int half = 0; half < 2; ++half) {
#pragma unroll
      for (int c = 0; c < 4; ++c) {
        int ct = half * 4 + c;
#pragma unroll
        for (int r = 0; r < 4; ++r)
          aSt[(lg * 4 + r) * 68 + c * 16 + lm] = acc[ct][r];
      }
#pragma unroll
      for (int i = 0; i < 4; ++i) {
        int o = l * 4 + i * 256;
        int row = o >> 6, col = o & 63;
        f32x4 v = *(const f32x4*)(aSt + row * 68 + col);
        *(f32x4*)(xdst + row * 128 + half * 64 + col) = v;
      }
    }
  }
}

extern "C" void kernel_launch(void* const* d_in, const int* in_sizes, int n_in,
                              void* d_out, int out_size, void* d_ws, size_t ws_size,
                              hipStream_t stream) {
  const float* q    = (const float*)d_in[0];
  const float* kv   = (const float*)d_in[1];
  const float* mask = (const float*)d_in[2];
  const float* qw   = (const float*)d_in[3];
  const float* qb   = (const float*)d_in[4];
  const float* kvw  = (const float*)d_in[5];
  const float* kvb  = (const float*)d_in[6];
  const float* pw   = (const float*)d_in[7];
  const float* pb   = (const float*)d_in[8];
  const float* rpb  = (const float*)d_in[9];
  const int* relidx = (const int*)d_in[10];

  float* xout = (float*)d_out;
  float* attn = xout + (size_t)1024 * 256 * 128;   // 33,554,432

  char* ws = (char*)d_ws;
  unsigned short* qwb  = (unsigned short*)ws;                 // 32 KB
  unsigned short* kvwb = (unsigned short*)(ws + 32768);       // 64 KB
  unsigned short* pwb  = (unsigned short*)(ws + 98304);       // 32 KB
  float*          bm   = (float*)(ws + 131072);               // 32 MB
  unsigned short* kws  = (unsigned short*)(ws + 131072 + 33554432);  // 32 MB
  unsigned short* vT   = kws + (size_t)16777216;              // 32 MB

  kw_prep<<<2048, 256, 0, stream>>>(qw, kvw, pw, rpb, relidx, mask, qwb, kvwb, pwb, bm);
  kkv<<<2048, 256, 0, stream>>>(kv, kvwb, kvb, kws, vT);
  kfused<<<4096, 256, 0, stream>>>(q, qwb, qb, kws, vT, bm, pwb, pb, attn, xout);
}

// Round 10
// 413.304 us; speedup vs baseline: 1.1516x; 1.0113x over previous
//
#include <hip/hip_runtime.h>

// WindowAttention3D: B=1024, N1=256, N2=128, C=128, NH=4, hd=32, nW=64
// out = [x (1024*256*128 f32)] ++ [attn (1024*4*256*128 f32)]
// R10: window-major block ordering (co-resident blocks share bm slices) +
//      NT on write-once streams to protect L2/L3 residency of bm/K/V.

typedef __attribute__((ext_vector_type(8))) short s16x8;
typedef __attribute__((ext_vector_type(4))) short s16x4;
typedef __attribute__((ext_vector_type(4))) float f32x4;

static __device__ __forceinline__ unsigned short f2bf(float f) {
  union { float f; unsigned u; } v; v.f = f;
  unsigned r = v.u + 0x7FFFu + ((v.u >> 16) & 1u);
  return (unsigned short)(r >> 16);
}

static __device__ __forceinline__ s16x8 cvt8(f32x4 a0, f32x4 a1) {
  s16x8 r;
  r[0] = (short)f2bf(a0[0]); r[1] = (short)f2bf(a0[1]);
  r[2] = (short)f2bf(a0[2]); r[3] = (short)f2bf(a0[3]);
  r[4] = (short)f2bf(a1[0]); r[5] = (short)f2bf(a1[1]);
  r[6] = (short)f2bf(a1[2]); r[7] = (short)f2bf(a1[3]);
  return r;
}

// ---------------- prep: weights->bf16, combined bias+mask table ----------------
__global__ void kw_prep(const float* __restrict__ qw, const float* __restrict__ kvw,
                        const float* __restrict__ pw, const float* __restrict__ rpb,
                        const int* __restrict__ relidx, const float* __restrict__ mask,
                        unsigned short* __restrict__ qwb, unsigned short* __restrict__ kvwb,
                        unsigned short* __restrict__ pwb, float* __restrict__ bm) {
  int tid = blockIdx.x * 256 + threadIdx.x;
  int stride = gridDim.x * 256;
  for (int i = tid; i < 65536; i += stride) {
    if (i < 16384)      qwb[i] = f2bf(qw[i]);
    else if (i < 49152) kvwb[i - 16384] = f2bf(kvw[i - 16384]);
    else                pwb[i - 49152] = f2bf(pw[i - 49152]);
  }
  for (int i = tid; i < 2097152; i += stride) {
    int wdw = i >> 15, j = i & 32767;
    int rel = relidx[j];
    float4 tv = *(const float4*)(rpb + rel * 4);
    float mk = mask[i];
    float* d = bm + (size_t)(wdw * 4) * 32768 + j;
    d[0]      = tv.x + mk;
    d[32768]  = tv.y + mk;
    d[65536]  = tv.z + mk;
    d[98304]  = tv.w + mk;
  }
}

// ---------------- kv projection: kws[b][h][n2][32], vT[b][h][dh][n2] ----------------
__global__ __launch_bounds__(256) void kkv(const float* __restrict__ kv,
    const unsigned short* __restrict__ kvwb, const float* __restrict__ kvb,
    unsigned short* __restrict__ kws, unsigned short* __restrict__ vT) {
  __shared__ unsigned short oK[64][136];
  __shared__ unsigned short oV[128][72];
  int b = blockIdx.x >> 1, r0 = (blockIdx.x & 1) << 6;
  int t = threadIdx.x;
  int w = t >> 6, l = t & 63, lm = l & 15, lg = l >> 4;
  const float* arow = kv + (size_t)(b * 128 + r0 + w * 16 + lm) * 128;
  f32x4 acc[16];
#pragma unroll
  for (int i = 0; i < 16; ++i) acc[i] = (f32x4){0.f, 0.f, 0.f, 0.f};
#pragma unroll
  for (int kk = 0; kk < 4; ++kk) {
    f32x4 a0 = __builtin_nontemporal_load((const f32x4*)(arow + kk * 32 + lg * 8));
    f32x4 a1 = __builtin_nontemporal_load((const f32x4*)(arow + kk * 32 + lg * 8 + 4));
    s16x8 a = cvt8(a0, a1);
#pragma unroll
    for (int ct = 0; ct < 16; ++ct) {
      s16x8 bf = *(const s16x8*)(kvwb + (ct * 16 + lm) * 128 + kk * 32 + lg * 8);
      acc[ct] = __builtin_amdgcn_mfma_f32_16x16x32_bf16(a, bf, acc[ct], 0, 0, 0);
    }
  }
#pragma unroll
  for (int ct = 0; ct < 16; ++ct) {
    int col = ct * 16 + lm;
    float bb = kvb[col];
    if (col < 128) {
#pragma unroll
      for (int r = 0; r < 4; ++r)
        oK[w * 16 + lg * 4 + r][col] = f2bf(acc[ct][r] + bb);
    } else {
      int d = col - 128;
      s16x4 pk;
#pragma unroll
      for (int r = 0; r < 4; ++r) pk[r] = (short)f2bf(acc[ct][r] + bb);
      *(s16x4*)&oV[d][w * 16 + lg * 4] = pk;
    }
  }
  __syncthreads();
  {
    int o = t * 8, row = o >> 5, cs = o & 31;
#pragma unroll
    for (int h = 0; h < 4; ++h) {
      s16x8 v = *(const s16x8*)&oK[row][h * 32 + cs];
      *(s16x8*)(kws + ((size_t)(b * 4 + h) * 128 + r0 + row) * 32 + cs) = v;
    }
  }
#pragma unroll
  for (int i = 0; i < 4; ++i) {
    int o = (t + i * 256) * 8;
    int d = o >> 6, ns = o & 63;
    s16x8 v = *(const s16x8*)&oV[d][ns];
    *(s16x8*)(vT + ((size_t)b * 128 + d) * 128 + r0 + ns) = v;
  }
}

// ---------------- fused: q-proj + attention + out-proj per (b, 64 q rows) ----------------
__global__ __launch_bounds__(256, 3) void kfused(const float* __restrict__ q,
    const unsigned short* __restrict__ qwb, const float* __restrict__ qb,
    const unsigned short* __restrict__ kws, const unsigned short* __restrict__ vT,
    const float* __restrict__ bm, const unsigned short* __restrict__ pwb,
    const float* __restrict__ pb, float* __restrict__ attn_out,
    float* __restrict__ xout) {
  __shared__ unsigned short qhL[64][136];   // qh tile, all heads
  __shared__ unsigned short XL[64][136];    // attention output tile, all heads
  __shared__ float scratch[4][1088] __attribute__((aligned(16))); // per-wave aSt[16][68]
  int bid = blockIdx.x;
  // window-major ordering: co-resident blocks share the same few bm windows;
  // the 4 q0-blocks of one b are adjacent (K/V L2-hot).
  int wdw = bid >> 6, r = bid & 63;
  int b = wdw + (r >> 2) * 64;
  int q0 = (r & 3) << 6;
  int t = threadIdx.x;
  int w = t >> 6, l = t & 63, lm = l & 15, lg = l >> 4;
  float* aSt = scratch[w];                  // [16][68] f32
  const f32x4 zero = {0.f, 0.f, 0.f, 0.f};

  // ---- Phase 1: q-proj, wave w -> rows w*16..w*16+15 ----
  {
    const float* arow = q + (size_t)(b * 256 + q0 + w * 16 + lm) * 128;
    f32x4 acc[8];
#pragma unroll
    for (int i = 0; i < 8; ++i) acc[i] = zero;
#pragma unroll
    for (int kk = 0; kk < 4; ++kk) {
      f32x4 a0 = __builtin_nontemporal_load((const f32x4*)(arow + kk * 32 + lg * 8));
      f32x4 a1 = __builtin_nontemporal_load((const f32x4*)(arow + kk * 32 + lg * 8 + 4));
      s16x8 a = cvt8(a0, a1);
#pragma unroll
      for (int ct = 0; ct < 8; ++ct) {
        s16x8 bf = *(const s16x8*)(qwb + (ct * 16 + lm) * 128 + kk * 32 + lg * 8);
        acc[ct] = __builtin_amdgcn_mfma_f32_16x16x32_bf16(a, bf, acc[ct], 0, 0, 0);
      }
    }
    const float SC = 0.17677669529663687f;   // 32^-0.5
#pragma unroll
    for (int ct = 0; ct < 8; ++ct) {
      int col = ct * 16 + lm;
      float bb = qb[col];
#pragma unroll
      for (int r2 = 0; r2 < 4; ++r2)
        qhL[w * 16 + lg * 4 + r2][col] = f2bf((acc[ct][r2] + bb) * SC);
    }
  }
  __syncthreads();

  // ---- Phase 2: attention, wave w = head h, 4 subtiles of 16 q-rows ----
  {
    int h = w;
    const unsigned short* ksrc = kws + (size_t)(b * 4 + h) * 4096;
    const unsigned short* vsrc = vT + (size_t)(b * 4 + h) * 4096;
    const float* bmh = bm + (size_t)(wdw * 4 + h) * 32768;
    float* attnh = attn_out + ((size_t)(b * 4 + h) * 256 + q0) * 128;
    for (int qt = 0; qt < 4; ++qt) {
      int qg = q0 + qt * 16 + lm;
      s16x8 bq = *(const s16x8*)&qhL[qt * 16 + lm][h * 32 + lg * 8];
      f32x4 S[8];  // S^T: row n2 = ct*16+lg*4+r, col q = lm
#pragma unroll
      for (int ct = 0; ct < 8; ++ct) {
        s16x8 ak = *(const s16x8*)(ksrc + (ct * 16 + lm) * 32 + lg * 8);
        S[ct] = __builtin_amdgcn_mfma_f32_16x16x32_bf16(ak, bq, zero, 0, 0, 0);
      }
      float m = -1e30f;
#pragma unroll
      for (int ct = 0; ct < 8; ++ct) {
        float4 bv = *(const float4*)(bmh + (size_t)qg * 128 + ct * 16 + lg * 4);
        S[ct][0] += bv.x; S[ct][1] += bv.y; S[ct][2] += bv.z; S[ct][3] += bv.w;
        m = fmaxf(m, fmaxf(fmaxf(S[ct][0], S[ct][1]), fmaxf(S[ct][2], S[ct][3])));
      }
      m = fmaxf(m, __shfl_xor(m, 16));
      m = fmaxf(m, __shfl_xor(m, 32));
      float s = 0.f;
#pragma unroll
      for (int ct = 0; ct < 8; ++ct) {
#pragma unroll
        for (int r2 = 0; r2 < 4; ++r2) { S[ct][r2] = __expf(S[ct][r2] - m); s += S[ct][r2]; }
      }
      s += __shfl_xor(s, 16);
      s += __shfl_xor(s, 32);
      float inv = 1.0f / s;
      float* adst = attnh + qt * 16 * 128;
      s16x8 pfrag[4];
      // two half-tiles of 16 q-rows x 64 n2 through per-wave aSt
#pragma unroll
      for (int half = 0; half < 2; ++half) {
#pragma unroll
        for (int c = 0; c < 4; ++c) {
          int ct = half * 4 + c;
          f32x4 pv = { S[ct][0] * inv, S[ct][1] * inv, S[ct][2] * inv, S[ct][3] * inv };
          *(f32x4*)(aSt + lm * 68 + c * 16 + lg * 4) = pv;
        }
        // NT store: 16 rows x 256B (2 full 128B lines per segment)
#pragma unroll
        for (int i = 0; i < 4; ++i) {
          int o = l * 4 + i * 256;
          int row = o >> 6, col = o & 63;
          f32x4 v = *(const f32x4*)(aSt + row * 68 + col);
          __builtin_nontemporal_store(v, (f32x4*)(adst + row * 128 + half * 64 + col));
        }
#pragma unroll
        for (int k2 = 0; k2 < 2; ++k2) {
          const float* pp = aSt + lm * 68 + k2 * 32 + lg * 8;
          pfrag[half * 2 + k2] = cvt8(*(const f32x4*)pp, *(const f32x4*)(pp + 4));
        }
      }
      // PV
      f32x4 O[2];
      O[0] = zero; O[1] = zero;
#pragma unroll
      for (int kk = 0; kk < 4; ++kk) {
#pragma unroll
        for (int cd = 0; cd < 2; ++cd) {
          s16x8 av = *(const s16x8*)(vsrc + (cd * 16 + lm) * 128 + kk * 32 + lg * 8);
          O[cd] = __builtin_amdgcn_mfma_f32_16x16x32_bf16(av, pfrag[kk], O[cd], 0, 0, 0);
        }
      }
#pragma unroll
      for (int cd = 0; cd < 2; ++cd) {
        s16x4 pk;
#pragma unroll
        for (int r2 = 0; r2 < 4; ++r2) pk[r2] = (short)f2bf(O[cd][r2]);
        *(s16x4*)&XL[qt * 16 + lm][h * 32 + cd * 16 + lg * 4] = pk;
      }
    }
  }
  __syncthreads();

  // ---- Phase 3: out-proj, wave w -> rows w*16..w*16+15 ----
  {
    f32x4 acc[8];
#pragma unroll
    for (int i = 0; i < 8; ++i) acc[i] = zero;
#pragma unroll
    for (int kk = 0; kk < 4; ++kk) {
      s16x8 a = *(const s16x8*)&XL[w * 16 + lm][kk * 32 + lg * 8];
#pragma unroll
      for (int ct = 0; ct < 8; ++ct) {
        s16x8 bf = *(const s16x8*)(pwb + (ct * 16 + lm) * 128 + kk * 32 + lg * 8);
        acc[ct] = __builtin_amdgcn_mfma_f32_16x16x32_bf16(a, bf, acc[ct], 0, 0, 0);
      }
    }
#pragma unroll
    for (int ct = 0; ct < 8; ++ct) {
      int col = ct * 16 + lm;
      float bb = pb[col];
#pragma unroll
      for (int r2 = 0; r2 < 4; ++r2) acc[ct][r2] += bb;
    }
    float* xdst = xout + ((size_t)b * 256 + q0 + w * 16) * 128;
#pragma unroll
    for (int half = 0; half < 2; ++half) {
#pragma unroll
      for (int c = 0; c < 4; ++c) {
        int ct = half * 4 + c;
#pragma unroll
        for (int r2 = 0; r2 < 4; ++r2)
          aSt[(lg * 4 + r2) * 68 + c * 16 + lm] = acc[ct][r2];
      }
#pragma unroll
      for (int i = 0; i < 4; ++i) {
        int o = l * 4 + i * 256;
        int row = o >> 6, col = o & 63;
        f32x4 v = *(const f32x4*)(aSt + row * 68 + col);
        __builtin_nontemporal_store(v, (f32x4*)(xdst + row * 128 + half * 64 + col));
      }
    }
  }
}

extern "C" void kernel_launch(void* const* d_in, const int* in_sizes, int n_in,
                              void* d_out, int out_size, void* d_ws, size_t ws_size,
                              hipStream_t stream) {
  const float* q    = (const float*)d_in[0];
  const float* kv   = (const float*)d_in[1];
  const float* mask = (const float*)d_in[2];
  const float* qw   = (const float*)d_in[3];
  const float* qb   = (const float*)d_in[4];
  const float* kvw  = (const float*)d_in[5];
  const float* kvb  = (const float*)d_in[6];
  const float* pw   = (const float*)d_in[7];
  const float* pb   = (const float*)d_in[8];
  const float* rpb  = (const float*)d_in[9];
  const int* relidx = (const int*)d_in[10];

  float* xout = (float*)d_out;
  float* attn = xout + (size_t)1024 * 256 * 128;   // 33,554,432

  char* ws = (char*)d_ws;
  unsigned short* qwb  = (unsigned short*)ws;                 // 32 KB
  unsigned short* kvwb = (unsigned short*)(ws + 32768);       // 64 KB
  unsigned short* pwb  = (unsigned short*)(ws + 98304);       // 32 KB
  float*          bm   = (float*)(ws + 131072);               // 32 MB
  unsigned short* kws  = (unsigned short*)(ws + 131072 + 33554432);  // 32 MB
  unsigned short* vT   = kws + (size_t)16777216;              // 32 MB

  kw_prep<<<2048, 256, 0, stream>>>(qw, kvw, pw, rpb, relidx, mask, qwb, kvwb, pwb, bm);
  kkv<<<2048, 256, 0, stream>>>(kv, kvwb, kvb, kws, vT);
  kfused<<<4096, 256, 0, stream>>>(q, qwb, qb, kws, vT, bm, pwb, pb, attn, xout);
}